// Round 4
// baseline (345.807 us; speedup 1.0000x reference)
//
#include <hip/hip_runtime.h>

#define DEV_INLINE __device__ __forceinline__
#define MEM_FENCE asm volatile("" ::: "memory")

typedef __bf16 bf16x8 __attribute__((ext_vector_type(8)));
typedef float  floatx4 __attribute__((ext_vector_type(4)));

DEV_INLINE bf16x8 ld_frag(const __bf16* p) {
    union { uint4 u; bf16x8 v; } t;
    t.u = *(const uint4*)p;
    return t.v;
}
DEV_INLINE void st4_relu(__bf16* p, floatx4 a) {
    union { __bf16 h[4]; uint2 u; } t;
#pragma unroll
    for (int i = 0; i < 4; ++i) t.h[i] = (__bf16)fmaxf(a[i], 0.0f);
    *(uint2*)p = t.u;
}

// ---------------------------------------------------------------------------
// Prep: transpose + zero-pad + cvt weights into bf16 A-operand layout
// wt[n_out][k_pad] (k contiguous, 16B rows).
// ---------------------------------------------------------------------------
template<int N, int Kp, int Ks>
DEV_INLINE void tp(__bf16* dst, const float* __restrict__ src, int idx0, int stride) {
    for (int e = idx0; e < N * Kp; e += stride) {
        int n = e / Kp, k = e - n * Kp;
        dst[e] = (k < Ks) ? (__bf16)src[k * N + n] : (__bf16)0.0f;
    }
}

__global__ __launch_bounds__(256)
void prep_kernel(const float* __restrict__ rw1, const float* __restrict__ rw2,
                 const float* __restrict__ rw3,
                 const float* __restrict__ tw1, const float* __restrict__ tw2,
                 const float* __restrict__ tw3,
                 const float* __restrict__ mw1, const float* __restrict__ mw2,
                 const float* __restrict__ mw3, __bf16* __restrict__ wb)
{
    int i0 = blockIdx.x * 256 + threadIdx.x;
    int st = gridDim.x * 256;
    tp< 64,  32,   6>(wb + 0,     rw1, i0, st);
    tp< 64,  64,  64>(wb + 2048,  rw2, i0, st);
    tp< 32,  64,  64>(wb + 6144,  rw3, i0, st);
    tp< 64,  32,   7>(wb + 8192,  tw1, i0, st);
    tp< 64,  64,  64>(wb + 10240, tw2, i0, st);
    tp< 32,  64,  64>(wb + 14336, tw3, i0, st);
    tp<128, 128, 108>(wb + 16384, mw1, i0, st);
    tp<128, 128, 128>(wb + 32768, mw2, i0, st);
    tp< 64, 128, 128>(wb + 49152, mw3, i0, st);
}

// ---------------------------------------------------------------------------
// MFMA set encoder, single aliased LDS buffer (h1 -> h2 -> e3 all in hs):
// rows are wave-private until the pre-pool barrier; DS pipe is in-order per
// wave, so read-before-overwrite is safe (MEM_FENCE stops TBAA reordering).
// LDS = 20.5 KB -> 7 blocks/CU (28 waves/CU).
// ---------------------------------------------------------------------------
template<int DIN, int S>
__global__ __launch_bounds__(256)
void enc_mfma(const float* __restrict__ X,
              const __bf16* __restrict__ wt1, const float* __restrict__ b1,
              const __bf16* __restrict__ wt2, const float* __restrict__ b2,
              const __bf16* __restrict__ wt3, const float* __restrict__ b3,
              __bf16* __restrict__ out)
{
    constexpr int NB = 128 / S;
    __shared__ __align__(16) __bf16 hs[128 * 72];   // h1 / h2 / e3([128][36] f32)
    __shared__ float pool[512];
    float* e3 = (float*)hs;

    const int tid = threadIdx.x;
    const int w   = tid >> 6;                // wave owns rows 32w..32w+31
    const int l64 = tid & 63;
    const int ln  = l64 & 15;
    const int qd  = l64 >> 4;

    // ---- L1: K=32 (zero-padded from DIN), B-frag = x rows ----
    bf16x8 xb[2];
#pragma unroll
    for (int t = 0; t < 2; ++t) {
        int row = (2 * w + t) * 16 + ln;
        const float* xp = X + ((size_t)blockIdx.x * 128 + row) * DIN;
        bf16x8 v;
#pragma unroll
        for (int j = 0; j < 8; ++j) v[j] = (__bf16)0.0f;
        if (qd == 0) {
#pragma unroll
            for (int j = 0; j < DIN; ++j) v[j] = (__bf16)xp[j];
        }
        xb[t] = v;
    }
#pragma unroll
    for (int mt = 0; mt < 4; ++mt) {
        bf16x8 af = ld_frag(&wt1[(mt * 16 + ln) * 32 + qd * 8]);
        float4 bv = *(const float4*)&b1[mt * 16 + qd * 4];
#pragma unroll
        for (int t = 0; t < 2; ++t) {
            floatx4 acc = (floatx4){bv.x, bv.y, bv.z, bv.w};
            acc = __builtin_amdgcn_mfma_f32_16x16x32_bf16(af, xb[t], acc, 0, 0, 0);
            st4_relu(&hs[((2 * w + t) * 16 + ln) * 72 + mt * 16 + qd * 4], acc);
        }
    }

    // ---- L2: 64 -> 64 (read h1 rows fully into regs, then overwrite) ----
    {
        bf16x8 bfr[2][2];
#pragma unroll
        for (int t = 0; t < 2; ++t)
#pragma unroll
            for (int kq = 0; kq < 2; ++kq)
                bfr[t][kq] = ld_frag(&hs[((2 * w + t) * 16 + ln) * 72 + kq * 32 + qd * 8]);
        MEM_FENCE;
#pragma unroll
        for (int mt = 0; mt < 4; ++mt) {
            bf16x8 a0 = ld_frag(&wt2[(mt * 16 + ln) * 64 + qd * 8]);
            bf16x8 a1 = ld_frag(&wt2[(mt * 16 + ln) * 64 + 32 + qd * 8]);
            float4 bv = *(const float4*)&b2[mt * 16 + qd * 4];
#pragma unroll
            for (int t = 0; t < 2; ++t) {
                floatx4 acc = (floatx4){bv.x, bv.y, bv.z, bv.w};
                acc = __builtin_amdgcn_mfma_f32_16x16x32_bf16(a0, bfr[t][0], acc, 0, 0, 0);
                acc = __builtin_amdgcn_mfma_f32_16x16x32_bf16(a1, bfr[t][1], acc, 0, 0, 0);
                st4_relu(&hs[((2 * w + t) * 16 + ln) * 72 + mt * 16 + qd * 4], acc);
            }
        }
    }

    // ---- L3: 64 -> 32, fp32 e3 overwrites same bytes (TBAA-fenced) ----
    {
        bf16x8 bfr[2][2];
#pragma unroll
        for (int t = 0; t < 2; ++t)
#pragma unroll
            for (int kq = 0; kq < 2; ++kq)
                bfr[t][kq] = ld_frag(&hs[((2 * w + t) * 16 + ln) * 72 + kq * 32 + qd * 8]);
        MEM_FENCE;
#pragma unroll
        for (int mt = 0; mt < 2; ++mt) {
            bf16x8 a0 = ld_frag(&wt3[(mt * 16 + ln) * 64 + qd * 8]);
            bf16x8 a1 = ld_frag(&wt3[(mt * 16 + ln) * 64 + 32 + qd * 8]);
            float4 bv = *(const float4*)&b3[mt * 16 + qd * 4];
#pragma unroll
            for (int t = 0; t < 2; ++t) {
                floatx4 acc = (floatx4){bv.x, bv.y, bv.z, bv.w};
                acc = __builtin_amdgcn_mfma_f32_16x16x32_bf16(a0, bfr[t][0], acc, 0, 0, 0);
                acc = __builtin_amdgcn_mfma_f32_16x16x32_bf16(a1, bfr[t][1], acc, 0, 0, 0);
                float4 o = {acc[0], acc[1], acc[2], acc[3]};
                *(float4*)&e3[((2 * w + t) * 16 + ln) * 36 + mt * 16 + qd * 4] = o;
            }
        }
    }
    __syncthreads();

    // ---- pool (mean+max)/2 over S rows per batch ----
    {
        const int o  = tid & 31;
        const int bi = (tid >> 5) % NB;
        const int ch = tid / (32 * NB);
        float s = 0.0f, m = -3.4e38f;
#pragma unroll
        for (int r = 0; r < 16; ++r) {
            float v = e3[(bi * S + ch * 16 + r) * 36 + o];
            s += v;
            m = fmaxf(m, v);
        }
        pool[tid] = s;
        pool[256 + tid] = m;
    }
    __syncthreads();
    if (tid < NB * 32) {
        constexpr int C = 8 / NB;
        float s = 0.0f, m = -3.4e38f;
#pragma unroll
        for (int c = 0; c < C; ++c) {
            s += pool[tid + c * 32 * NB];
            m = fmaxf(m, pool[256 + tid + c * 32 * NB]);
        }
        size_t b = (size_t)blockIdx.x * NB + (tid >> 5);
        out[b * 32 + (tid & 31)] = (__bf16)(0.5f * (s * (1.0f / S) + m));
    }
}

// ---------------------------------------------------------------------------
// Head, barrier-free: each wave owns 16 rows end-to-end. concat[108 pad 128]
// -> 128 -> 128 -> 64 (MFMA bf16) -> 1 (fp32 dot + shfl_xor reduce).
// ---------------------------------------------------------------------------
__global__ __launch_bounds__(256)
void head_mfma(const float* __restrict__ t0,
               const __bf16* __restrict__ remb, const __bf16* __restrict__ temb,
               const __bf16* __restrict__ hw1, const float* __restrict__ b1,
               const __bf16* __restrict__ hw2, const float* __restrict__ b2,
               const __bf16* __restrict__ hw3, const float* __restrict__ b3,
               const float* __restrict__ w4, const float* __restrict__ b4,
               float* __restrict__ out)
{
    __shared__ __align__(16) __bf16 cb[4][16 * 136];   // c, then h2
    __shared__ __align__(16) __bf16 hb[4][16 * 136];   // h1
    __shared__ __align__(16) __bf16 h3[4][16 * 72];

    const int tid = threadIdx.x;
    const int w   = tid >> 6;
    const int l64 = tid & 63;
    const int ln  = l64 & 15;
    const int qd  = l64 >> 4;
    const int g0  = blockIdx.x * 64;
    const int r0  = g0 + 16 * w;             // this wave's first row

    // ---- stage c[108] = [tier0(44)|remb(32)|temb(32)] + pad, wave-private ----
    for (int i = l64; i < 16 * 44; i += 64) {
        int r = i / 44, k = i - r * 44;
        cb[w][r * 136 + k] = (__bf16)t0[(size_t)(r0 + r) * 44 + i - r * 44 + 0 * k];
    }
    for (int i = l64; i < 16 * 32; i += 64) {
        int r = i >> 5, k = i & 31;
        cb[w][r * 136 + 44 + k] = remb[(size_t)(r0 + r) * 32 + k];
        cb[w][r * 136 + 76 + k] = temb[(size_t)(r0 + r) * 32 + k];
    }
    for (int i = l64; i < 16 * 20; i += 64) {
        int r = i / 20, k = i - r * 20;
        cb[w][r * 136 + 108 + k] = (__bf16)0.0f;
    }
    MEM_FENCE;   // wave-private LDS: DS pipe in-order, no barrier needed

    // ---- L1: 128 -> 128, B-frags reused across all 8 m-tiles ----
    {
        bf16x8 bfr[4];
#pragma unroll
        for (int kq = 0; kq < 4; ++kq)
            bfr[kq] = ld_frag(&cb[w][ln * 136 + kq * 32 + qd * 8]);
#pragma unroll
        for (int mt = 0; mt < 8; ++mt) {
            bf16x8 af[4];
#pragma unroll
            for (int kq = 0; kq < 4; ++kq)
                af[kq] = ld_frag(&hw1[(mt * 16 + ln) * 128 + kq * 32 + qd * 8]);
            float4 bv = *(const float4*)&b1[mt * 16 + qd * 4];
            floatx4 acc = (floatx4){bv.x, bv.y, bv.z, bv.w};
#pragma unroll
            for (int kq = 0; kq < 4; ++kq)
                acc = __builtin_amdgcn_mfma_f32_16x16x32_bf16(af[kq], bfr[kq], acc, 0, 0, 0);
            st4_relu(&hb[w][ln * 136 + mt * 16 + qd * 4], acc);
        }
    }

    // ---- L2: 128 -> 128 (hb -> cb, overwrites c after reads) ----
    {
        bf16x8 bfr[4];
#pragma unroll
        for (int kq = 0; kq < 4; ++kq)
            bfr[kq] = ld_frag(&hb[w][ln * 136 + kq * 32 + qd * 8]);
        MEM_FENCE;
#pragma unroll
        for (int mt = 0; mt < 8; ++mt) {
            bf16x8 af[4];
#pragma unroll
            for (int kq = 0; kq < 4; ++kq)
                af[kq] = ld_frag(&hw2[(mt * 16 + ln) * 128 + kq * 32 + qd * 8]);
            float4 bv = *(const float4*)&b2[mt * 16 + qd * 4];
            floatx4 acc = (floatx4){bv.x, bv.y, bv.z, bv.w};
#pragma unroll
            for (int kq = 0; kq < 4; ++kq)
                acc = __builtin_amdgcn_mfma_f32_16x16x32_bf16(af[kq], bfr[kq], acc, 0, 0, 0);
            st4_relu(&cb[w][ln * 136 + mt * 16 + qd * 4], acc);
        }
    }

    // ---- L3: 128 -> 64 ----
    {
        bf16x8 bfr[4];
#pragma unroll
        for (int kq = 0; kq < 4; ++kq)
            bfr[kq] = ld_frag(&cb[w][ln * 136 + kq * 32 + qd * 8]);
#pragma unroll
        for (int mt = 0; mt < 4; ++mt) {
            bf16x8 af[4];
#pragma unroll
            for (int kq = 0; kq < 4; ++kq)
                af[kq] = ld_frag(&hw3[(mt * 16 + ln) * 128 + kq * 32 + qd * 8]);
            float4 bv = *(const float4*)&b3[mt * 16 + qd * 4];
            floatx4 acc = (floatx4){bv.x, bv.y, bv.z, bv.w};
#pragma unroll
            for (int kq = 0; kq < 4; ++kq)
                acc = __builtin_amdgcn_mfma_f32_16x16x32_bf16(af[kq], bfr[kq], acc, 0, 0, 0);
            st4_relu(&h3[w][ln * 72 + mt * 16 + qd * 4], acc);
        }
    }

    // ---- L4: 64 -> 1 fp32; lane (ln,qd): row ln, k-slice qd*16 ----
    {
        float part = 0.0f;
#pragma unroll
        for (int c = 0; c < 2; ++c) {
            bf16x8 hv = ld_frag(&h3[w][ln * 72 + qd * 16 + c * 8]);
            float4 w4a = *(const float4*)&w4[qd * 16 + c * 8];
            float4 w4b = *(const float4*)&w4[qd * 16 + c * 8 + 4];
            part = fmaf((float)hv[0], w4a.x, part);
            part = fmaf((float)hv[1], w4a.y, part);
            part = fmaf((float)hv[2], w4a.z, part);
            part = fmaf((float)hv[3], w4a.w, part);
            part = fmaf((float)hv[4], w4b.x, part);
            part = fmaf((float)hv[5], w4b.y, part);
            part = fmaf((float)hv[6], w4b.z, part);
            part = fmaf((float)hv[7], w4b.w, part);
        }
        part += __shfl_xor(part, 16);
        part += __shfl_xor(part, 32);
        if (qd == 0)
            out[r0 + ln] = part + b4[0];
    }
}

extern "C" void kernel_launch(void* const* d_in, const int* in_sizes, int n_in,
                              void* d_out, int out_size, void* d_ws, size_t ws_size,
                              hipStream_t stream)
{
    const float* t0  = (const float*)d_in[0];
    const float* rX  = (const float*)d_in[1];
    const float* tX  = (const float*)d_in[2];
    const float* rw1 = (const float*)d_in[3];  const float* rb1 = (const float*)d_in[4];
    const float* rw2 = (const float*)d_in[5];  const float* rb2 = (const float*)d_in[6];
    const float* rw3 = (const float*)d_in[7];  const float* rb3 = (const float*)d_in[8];
    const float* tw1 = (const float*)d_in[9];  const float* tb1 = (const float*)d_in[10];
    const float* tw2 = (const float*)d_in[11]; const float* tb2 = (const float*)d_in[12];
    const float* tw3 = (const float*)d_in[13]; const float* tb3 = (const float*)d_in[14];
    const float* mw1 = (const float*)d_in[15]; const float* mb1 = (const float*)d_in[16];
    const float* mw2 = (const float*)d_in[17]; const float* mb2 = (const float*)d_in[18];
    const float* mw3 = (const float*)d_in[19]; const float* mb3 = (const float*)d_in[20];
    const float* mw4 = (const float*)d_in[21]; const float* mb4 = (const float*)d_in[22];
    float* out = (float*)d_out;

    const int B = 16384;
    __bf16* remb = (__bf16*)d_ws;
    __bf16* temb = (__bf16*)((char*)d_ws + ((size_t)1 << 20));
    __bf16* wb   = (__bf16*)((char*)d_ws + ((size_t)2 << 20));
    const __bf16* rw1b = wb + 0;     const __bf16* rw2b = wb + 2048;
    const __bf16* rw3b = wb + 6144;
    const __bf16* tw1b = wb + 8192;  const __bf16* tw2b = wb + 10240;
    const __bf16* tw3b = wb + 14336;
    const __bf16* mw1b = wb + 16384; const __bf16* mw2b = wb + 32768;
    const __bf16* mw3b = wb + 49152;

    prep_kernel<<<64, 256, 0, stream>>>(rw1, rw2, rw3, tw1, tw2, tw3,
                                        mw1, mw2, mw3, wb);
    enc_mfma<6, 64> <<<(B * 64) / 128, 256, 0, stream>>>(
        rX, rw1b, rb1, rw2b, rb2, rw3b, rb3, remb);
    enc_mfma<7, 128><<<(B * 128) / 128, 256, 0, stream>>>(
        tX, tw1b, tb1, tw2b, tb2, tw3b, tb3, temb);
    head_mfma<<<B / 64, 256, 0, stream>>>(t0, remb, temb,
                                          mw1b, mb1, mw2b, mb2, mw3b, mb3,
                                          mw4, mb4, out);
}

// Round 5
// 302.492 us; speedup vs baseline: 1.1432x; 1.1432x over previous
//
#include <hip/hip_runtime.h>

#define DEV_INLINE __device__ __forceinline__
#define MEM_FENCE asm volatile("" ::: "memory")

typedef __bf16 bf16x8 __attribute__((ext_vector_type(8)));
typedef float  floatx4 __attribute__((ext_vector_type(4)));

DEV_INLINE bf16x8 ld_frag(const __bf16* p) {
    union { uint4 u; bf16x8 v; } t;
    t.u = *(const uint4*)p;
    return t.v;
}
DEV_INLINE void st4_relu(__bf16* p, floatx4 a) {
    union { __bf16 h[4]; uint2 u; } t;
#pragma unroll
    for (int i = 0; i < 4; ++i) t.h[i] = (__bf16)fmaxf(a[i], 0.0f);
    *(uint2*)p = t.u;
}

// ---------------------------------------------------------------------------
// Prep: transpose + zero-pad + cvt weights into bf16 A-operand layout
// wt[n_out][k_pad] (k contiguous, 16B rows). Encoder weights contiguous:
// robot at wb+0 (2048+4096+2048), track at wb+8192 (same), head after.
// ---------------------------------------------------------------------------
template<int N, int Kp, int Ks>
DEV_INLINE void tp(__bf16* dst, const float* __restrict__ src, int idx0, int stride) {
    for (int e = idx0; e < N * Kp; e += stride) {
        int n = e / Kp, k = e - n * Kp;
        dst[e] = (k < Ks) ? (__bf16)src[k * N + n] : (__bf16)0.0f;
    }
}

__global__ __launch_bounds__(256)
void prep_kernel(const float* __restrict__ rw1, const float* __restrict__ rw2,
                 const float* __restrict__ rw3,
                 const float* __restrict__ tw1, const float* __restrict__ tw2,
                 const float* __restrict__ tw3,
                 const float* __restrict__ mw1, const float* __restrict__ mw2,
                 const float* __restrict__ mw3, __bf16* __restrict__ wb)
{
    int i0 = blockIdx.x * 256 + threadIdx.x;
    int st = gridDim.x * 256;
    tp< 64,  32,   6>(wb + 0,     rw1, i0, st);
    tp< 64,  64,  64>(wb + 2048,  rw2, i0, st);
    tp< 32,  64,  64>(wb + 6144,  rw3, i0, st);
    tp< 64,  32,   7>(wb + 8192,  tw1, i0, st);
    tp< 64,  64,  64>(wb + 10240, tw2, i0, st);
    tp< 32,  64,  64>(wb + 14336, tw3, i0, st);
    tp<128, 128, 108>(wb + 16384, mw1, i0, st);
    tp<128, 128, 128>(wb + 32768, mw2, i0, st);
    tp< 64, 128, 128>(wb + 49152, mw3, i0, st);
}

// ---------------------------------------------------------------------------
// Fused MFMA set encoder (robot + track in one dispatch).
// Per block: stage weights(LDS, padded) + X(coalesced -> bf16 cols 0..31 of
// hs) once; then wave-private L1/L2/L3 MFMA with all operands from LDS.
// hs aliases: x -> h1 -> h2 -> e3(f32). pool aliases w1 (dead after L1).
// LDS = 38 KB -> 4 blocks/CU.
// ---------------------------------------------------------------------------
struct EncSmem {
    __bf16 hs[128 * 72];     // 18432 B: x/h1/h2, then e3 = f32 [128][36]
    __bf16 w1[64 * 40];      // 5120 B, row stride 40 (bank-safe)
    __bf16 w2[64 * 72];      // 9216 B, row stride 72
    __bf16 w3[32 * 72];      // 4608 B, row stride 72
    float  bs[160];          // 640 B: b1|b2|b3
};

template<int DIN, int S>
DEV_INLINE void enc_body(EncSmem& sm, const float* __restrict__ X,
                         const __bf16* __restrict__ wenc,
                         const float* __restrict__ b1, const float* __restrict__ b2,
                         const float* __restrict__ b3,
                         __bf16* __restrict__ out, int bid)
{
    constexpr int NB = 128 / S;
    const int tid = threadIdx.x;
    const int w   = tid >> 6;
    const int l64 = tid & 63;
    const int ln  = l64 & 15;
    const int qd  = l64 >> 4;
    float* e3   = (float*)sm.hs;
    float* pool = (float*)sm.w1;     // w1 dead after L1; pool used after barrier

    // ---- stage weights (uint4 copies into padded rows) ----
    {
        const uint4* wsrc = (const uint4*)wenc;   // [wt1 256 | wt2 512 | wt3 256] uint4s
        {
            int i = tid;                           // 256 uint4s of wt1 (rows of 4)
            int r = i >> 2, c = i & 3;
            *(uint4*)&sm.w1[r * 40 + c * 8] = wsrc[i];
        }
        for (int i = tid; i < 512; i += 256) {     // wt2: rows of 8
            int r = i >> 3, c = i & 7;
            *(uint4*)&sm.w2[r * 72 + c * 8] = wsrc[256 + i];
        }
        {
            int i = tid;                           // wt3: rows of 8
            int r = i >> 3, c = i & 7;
            *(uint4*)&sm.w3[r * 72 + c * 8] = wsrc[768 + i];
        }
        if (tid < 160)
            sm.bs[tid] = (tid < 64) ? b1[tid]
                       : (tid < 128) ? b2[tid - 64] : b3[tid - 128];
    }
    // ---- stage X: coalesced dword reads -> bf16, zero-pad k to 32 ----
    for (int i = tid; i < 128 * DIN; i += 256) {
        int r = i / DIN, k = i - r * DIN;
        sm.hs[r * 72 + k] = (__bf16)X[(size_t)bid * (128 * DIN) + i];
    }
    {
        constexpr int P = 32 - DIN;
        for (int i = tid; i < 128 * P; i += 256) {
            int r = i / P, k = i - r * P;
            sm.hs[r * 72 + DIN + k] = (__bf16)0.0f;
        }
    }
    __syncthreads();

    // ---- L1: K=32 -> 64 ----
    {
        bf16x8 xb[2];
#pragma unroll
        for (int t = 0; t < 2; ++t)
            xb[t] = ld_frag(&sm.hs[((2 * w + t) * 16 + ln) * 72 + qd * 8]);
        MEM_FENCE;
#pragma unroll
        for (int mt = 0; mt < 4; ++mt) {
            bf16x8 af = ld_frag(&sm.w1[(mt * 16 + ln) * 40 + qd * 8]);
            float4 bv = *(const float4*)&sm.bs[mt * 16 + qd * 4];
#pragma unroll
            for (int t = 0; t < 2; ++t) {
                floatx4 acc = (floatx4){bv.x, bv.y, bv.z, bv.w};
                acc = __builtin_amdgcn_mfma_f32_16x16x32_bf16(af, xb[t], acc, 0, 0, 0);
                st4_relu(&sm.hs[((2 * w + t) * 16 + ln) * 72 + mt * 16 + qd * 4], acc);
            }
        }
    }

    // ---- L2: 64 -> 64 ----
    {
        bf16x8 bfr[2][2];
#pragma unroll
        for (int t = 0; t < 2; ++t)
#pragma unroll
            for (int kq = 0; kq < 2; ++kq)
                bfr[t][kq] = ld_frag(&sm.hs[((2 * w + t) * 16 + ln) * 72 + kq * 32 + qd * 8]);
        MEM_FENCE;
#pragma unroll
        for (int mt = 0; mt < 4; ++mt) {
            bf16x8 a0 = ld_frag(&sm.w2[(mt * 16 + ln) * 72 + qd * 8]);
            bf16x8 a1 = ld_frag(&sm.w2[(mt * 16 + ln) * 72 + 32 + qd * 8]);
            float4 bv = *(const float4*)&sm.bs[64 + mt * 16 + qd * 4];
#pragma unroll
            for (int t = 0; t < 2; ++t) {
                floatx4 acc = (floatx4){bv.x, bv.y, bv.z, bv.w};
                acc = __builtin_amdgcn_mfma_f32_16x16x32_bf16(a0, bfr[t][0], acc, 0, 0, 0);
                acc = __builtin_amdgcn_mfma_f32_16x16x32_bf16(a1, bfr[t][1], acc, 0, 0, 0);
                st4_relu(&sm.hs[((2 * w + t) * 16 + ln) * 72 + mt * 16 + qd * 4], acc);
            }
        }
    }

    // ---- L3: 64 -> 32, fp32 e3 overwrites hs ----
    {
        bf16x8 bfr[2][2];
#pragma unroll
        for (int t = 0; t < 2; ++t)
#pragma unroll
            for (int kq = 0; kq < 2; ++kq)
                bfr[t][kq] = ld_frag(&sm.hs[((2 * w + t) * 16 + ln) * 72 + kq * 32 + qd * 8]);
        MEM_FENCE;
#pragma unroll
        for (int mt = 0; mt < 2; ++mt) {
            bf16x8 a0 = ld_frag(&sm.w3[(mt * 16 + ln) * 72 + qd * 8]);
            bf16x8 a1 = ld_frag(&sm.w3[(mt * 16 + ln) * 72 + 32 + qd * 8]);
            float4 bv = *(const float4*)&sm.bs[128 + mt * 16 + qd * 4];
#pragma unroll
            for (int t = 0; t < 2; ++t) {
                floatx4 acc = (floatx4){bv.x, bv.y, bv.z, bv.w};
                acc = __builtin_amdgcn_mfma_f32_16x16x32_bf16(a0, bfr[t][0], acc, 0, 0, 0);
                acc = __builtin_amdgcn_mfma_f32_16x16x32_bf16(a1, bfr[t][1], acc, 0, 0, 0);
                float4 o = {acc[0], acc[1], acc[2], acc[3]};
                *(float4*)&e3[((2 * w + t) * 16 + ln) * 36 + mt * 16 + qd * 4] = o;
            }
        }
    }
    __syncthreads();

    // ---- pool (mean+max)/2 over S rows per batch ----
    {
        const int o  = tid & 31;
        const int bi = (tid >> 5) % NB;
        const int ch = tid / (32 * NB);
        float s = 0.0f, m = -3.4e38f;
#pragma unroll
        for (int r = 0; r < 16; ++r) {
            float v = e3[(bi * S + ch * 16 + r) * 36 + o];
            s += v;
            m = fmaxf(m, v);
        }
        pool[tid] = s;
        pool[256 + tid] = m;
    }
    __syncthreads();
    if (tid < NB * 32) {
        constexpr int C = 8 / NB;
        float s = 0.0f, m = -3.4e38f;
#pragma unroll
        for (int c = 0; c < C; ++c) {
            s += pool[tid + c * 32 * NB];
            m = fmaxf(m, pool[256 + tid + c * 32 * NB]);
        }
        size_t b = (size_t)bid * NB + (tid >> 5);
        out[b * 32 + (tid & 31)] = (__bf16)(0.5f * (s * (1.0f / S) + m));
    }
}

__global__ __launch_bounds__(256)
void enc_fused(const float* __restrict__ rX, const float* __restrict__ tX,
               const __bf16* __restrict__ wb,
               const float* __restrict__ rb1, const float* __restrict__ rb2,
               const float* __restrict__ rb3,
               const float* __restrict__ tb1, const float* __restrict__ tb2,
               const float* __restrict__ tb3,
               __bf16* __restrict__ remb, __bf16* __restrict__ temb, int nr)
{
    __shared__ EncSmem sm;
    if ((int)blockIdx.x < nr)
        enc_body<6, 64>(sm, rX, wb, rb1, rb2, rb3, remb, blockIdx.x);
    else
        enc_body<7, 128>(sm, tX, wb + 8192, tb1, tb2, tb3, temb, blockIdx.x - nr);
}

// ---------------------------------------------------------------------------
// Head (R3 version): concat[108 pad 128] -> 128 -> 128 -> 64 (MFMA) -> 1.
// Waves m-split each layer; weights from global (prepped layout).
// ---------------------------------------------------------------------------
__global__ __launch_bounds__(256)
void head_mfma(const float* __restrict__ t0,
               const __bf16* __restrict__ remb, const __bf16* __restrict__ temb,
               const __bf16* __restrict__ hw1, const float* __restrict__ b1,
               const __bf16* __restrict__ hw2, const float* __restrict__ b2,
               const __bf16* __restrict__ hw3, const float* __restrict__ b3,
               const float* __restrict__ w4, const float* __restrict__ b4,
               float* __restrict__ out)
{
    __shared__ __align__(16) __bf16 cbuf[64 * 136];   // c, then h2
    __shared__ __align__(16) __bf16 hbuf[64 * 136];   // h1
    __shared__ __align__(16) __bf16 h3buf[64 * 72];
    __shared__ float pbuf[256];

    const int tid = threadIdx.x;
    const int w   = tid >> 6;
    const int l64 = tid & 63;
    const int ln  = l64 & 15;
    const int qd  = l64 >> 4;
    const int g0  = blockIdx.x * 64;

    for (int i = tid; i < 64 * 44; i += 256) {
        int r = i / 44, k = i - r * 44;
        cbuf[r * 136 + k] = (__bf16)t0[(size_t)(g0 + r) * 44 + k];
    }
    for (int i = tid; i < 64 * 32; i += 256) {
        int r = i >> 5, k = i & 31;
        cbuf[r * 136 + 44 + k] = remb[(size_t)(g0 + r) * 32 + k];
        cbuf[r * 136 + 76 + k] = temb[(size_t)(g0 + r) * 32 + k];
    }
    for (int i = tid; i < 64 * 20; i += 256) {
        int r = i / 20, k = i - r * 20;
        cbuf[r * 136 + 108 + k] = (__bf16)0.0f;
    }
    __syncthreads();

    // L1: 128-pad -> 128, wave w owns m-tiles {2w, 2w+1}
    {
        bf16x8 bfr[4][4];
#pragma unroll
        for (int nt = 0; nt < 4; ++nt)
#pragma unroll
            for (int kq = 0; kq < 4; ++kq)
                bfr[nt][kq] = ld_frag(&cbuf[(nt * 16 + ln) * 136 + kq * 32 + qd * 8]);
#pragma unroll
        for (int m2 = 0; m2 < 2; ++m2) {
            int mt = 2 * w + m2;
            bf16x8 af[4];
#pragma unroll
            for (int kq = 0; kq < 4; ++kq)
                af[kq] = ld_frag(&hw1[(mt * 16 + ln) * 128 + kq * 32 + qd * 8]);
            float4 bv = *(const float4*)&b1[mt * 16 + qd * 4];
#pragma unroll
            for (int nt = 0; nt < 4; ++nt) {
                floatx4 acc = (floatx4){bv.x, bv.y, bv.z, bv.w};
#pragma unroll
                for (int kq = 0; kq < 4; ++kq)
                    acc = __builtin_amdgcn_mfma_f32_16x16x32_bf16(af[kq], bfr[nt][kq], acc, 0, 0, 0);
                st4_relu(&hbuf[(nt * 16 + ln) * 136 + mt * 16 + qd * 4], acc);
            }
        }
    }
    __syncthreads();

    // L2: 128 -> 128 (hbuf -> cbuf)
    {
        bf16x8 bfr[4][4];
#pragma unroll
        for (int nt = 0; nt < 4; ++nt)
#pragma unroll
            for (int kq = 0; kq < 4; ++kq)
                bfr[nt][kq] = ld_frag(&hbuf[(nt * 16 + ln) * 136 + kq * 32 + qd * 8]);
        __syncthreads();
#pragma unroll
        for (int m2 = 0; m2 < 2; ++m2) {
            int mt = 2 * w + m2;
            bf16x8 af[4];
#pragma unroll
            for (int kq = 0; kq < 4; ++kq)
                af[kq] = ld_frag(&hw2[(mt * 16 + ln) * 128 + kq * 32 + qd * 8]);
            float4 bv = *(const float4*)&b2[mt * 16 + qd * 4];
#pragma unroll
            for (int nt = 0; nt < 4; ++nt) {
                floatx4 acc = (floatx4){bv.x, bv.y, bv.z, bv.w};
#pragma unroll
                for (int kq = 0; kq < 4; ++kq)
                    acc = __builtin_amdgcn_mfma_f32_16x16x32_bf16(af[kq], bfr[nt][kq], acc, 0, 0, 0);
                st4_relu(&cbuf[(nt * 16 + ln) * 136 + mt * 16 + qd * 4], acc);
            }
        }
    }
    __syncthreads();

    // L3: 128 -> 64, wave w owns m-tile w
    {
        bf16x8 af[4];
#pragma unroll
        for (int kq = 0; kq < 4; ++kq)
            af[kq] = ld_frag(&hw3[(w * 16 + ln) * 128 + kq * 32 + qd * 8]);
        float4 bv = *(const float4*)&b3[w * 16 + qd * 4];
#pragma unroll
        for (int nt = 0; nt < 4; ++nt) {
            floatx4 acc = (floatx4){bv.x, bv.y, bv.z, bv.w};
#pragma unroll
            for (int kq = 0; kq < 4; ++kq) {
                bf16x8 bfr = ld_frag(&cbuf[(nt * 16 + ln) * 136 + kq * 32 + qd * 8]);
                acc = __builtin_amdgcn_mfma_f32_16x16x32_bf16(af[kq], bfr, acc, 0, 0, 0);
            }
            st4_relu(&h3buf[(nt * 16 + ln) * 72 + w * 16 + qd * 4], acc);
        }
    }
    __syncthreads();

    // L4: 64 -> 1, fp32; wave w handles k-slice [16w, 16w+16)
    {
        const int r = tid & 63;
        float part = 0.0f;
#pragma unroll
        for (int c = 0; c < 2; ++c) {
            bf16x8 hv = ld_frag(&h3buf[r * 72 + w * 16 + c * 8]);
#pragma unroll
            for (int u = 0; u < 8; ++u)
                part = fmaf((float)hv[u], w4[w * 16 + c * 8 + u], part);
        }
        pbuf[w * 64 + r] = part;
    }
    __syncthreads();
    if (tid < 64)
        out[g0 + tid] = pbuf[tid] + pbuf[64 + tid] + pbuf[128 + tid] +
                        pbuf[192 + tid] + b4[0];
}

extern "C" void kernel_launch(void* const* d_in, const int* in_sizes, int n_in,
                              void* d_out, int out_size, void* d_ws, size_t ws_size,
                              hipStream_t stream)
{
    const float* t0  = (const float*)d_in[0];
    const float* rX  = (const float*)d_in[1];
    const float* tX  = (const float*)d_in[2];
    const float* rw1 = (const float*)d_in[3];  const float* rb1 = (const float*)d_in[4];
    const float* rw2 = (const float*)d_in[5];  const float* rb2 = (const float*)d_in[6];
    const float* rw3 = (const float*)d_in[7];  const float* rb3 = (const float*)d_in[8];
    const float* tw1 = (const float*)d_in[9];  const float* tb1 = (const float*)d_in[10];
    const float* tw2 = (const float*)d_in[11]; const float* tb2 = (const float*)d_in[12];
    const float* tw3 = (const float*)d_in[13]; const float* tb3 = (const float*)d_in[14];
    const float* mw1 = (const float*)d_in[15]; const float* mb1 = (const float*)d_in[16];
    const float* mw2 = (const float*)d_in[17]; const float* mb2 = (const float*)d_in[18];
    const float* mw3 = (const float*)d_in[19]; const float* mb3 = (const float*)d_in[20];
    const float* mw4 = (const float*)d_in[21]; const float* mb4 = (const float*)d_in[22];
    float* out = (float*)d_out;

    const int B = 16384;
    __bf16* remb = (__bf16*)d_ws;
    __bf16* temb = (__bf16*)((char*)d_ws + ((size_t)1 << 20));
    __bf16* wb   = (__bf16*)((char*)d_ws + ((size_t)2 << 20));
    const __bf16* mw1b = wb + 16384; const __bf16* mw2b = wb + 32768;
    const __bf16* mw3b = wb + 49152;

    prep_kernel<<<64, 256, 0, stream>>>(rw1, rw2, rw3, tw1, tw2, tw3,
                                        mw1, mw2, mw3, wb);
    const int nr = (B * 64) / 128;                       // 8192 robot blocks
    const int nt = (B * 128) / 128;                      // 16384 track blocks
    enc_fused<<<nr + nt, 256, 0, stream>>>(rX, tX, wb,
                                           rb1, rb2, rb3, tb1, tb2, tb3,
                                           remb, temb, nr);
    head_mfma<<<B / 64, 256, 0, stream>>>(t0, remb, temb,
                                          mw1b, mb1, mw2b, mb2, mw3b, mb3,
                                          mw4, mb4, out);
}

// Round 6
// 274.809 us; speedup vs baseline: 1.2584x; 1.1007x over previous
//
#include <hip/hip_runtime.h>
#include <hip/hip_bf16.h>

#define DEV_INLINE __device__ __forceinline__
#define MEM_FENCE asm volatile("" ::: "memory")

typedef __bf16 bf16x8 __attribute__((ext_vector_type(8)));
typedef float  floatx4 __attribute__((ext_vector_type(4)));

DEV_INLINE bf16x8 ld_frag(const __bf16* p) {
    union { uint4 u; bf16x8 v; } t;
    t.u = *(const uint4*)p;
    return t.v;
}
// relu + packed f32->bf16 (v_cvt_pk_bf16_f32) + single b64 store
DEV_INLINE void st4_relu(__bf16* p, floatx4 a) {
    float2 lo = {fmaxf(a[0], 0.0f), fmaxf(a[1], 0.0f)};
    float2 hi = {fmaxf(a[2], 0.0f), fmaxf(a[3], 0.0f)};
    union { __hip_bfloat162 h[2]; uint2 u; } t;
    t.h[0] = __float22bfloat162_rn(lo);
    t.h[1] = __float22bfloat162_rn(hi);
    *(uint2*)p = t.u;
}

// ---------------------------------------------------------------------------
// Prep: transpose + zero-pad + cvt weights into bf16 A-operand layout
// wt[n_out][k_pad] (k contiguous, 16B rows). Layout identical to R5.
// ---------------------------------------------------------------------------
template<int N, int Kp, int Ks>
DEV_INLINE void tp(__bf16* dst, const float* __restrict__ src, int idx0, int stride) {
    for (int e = idx0; e < N * Kp; e += stride) {
        int n = e / Kp, k = e - n * Kp;
        dst[e] = (k < Ks) ? (__bf16)src[k * N + n] : (__bf16)0.0f;
    }
}

__global__ __launch_bounds__(256)
void prep_kernel(const float* __restrict__ rw1, const float* __restrict__ rw2,
                 const float* __restrict__ rw3,
                 const float* __restrict__ tw1, const float* __restrict__ tw2,
                 const float* __restrict__ tw3,
                 const float* __restrict__ mw1, const float* __restrict__ mw2,
                 const float* __restrict__ mw3, __bf16* __restrict__ wb)
{
    int i0 = blockIdx.x * 256 + threadIdx.x;
    int st = gridDim.x * 256;
    tp< 64,  32,   6>(wb + 0,     rw1, i0, st);
    tp< 64,  64,  64>(wb + 2048,  rw2, i0, st);
    tp< 32,  64,  64>(wb + 6144,  rw3, i0, st);
    tp< 64,  32,   7>(wb + 8192,  tw1, i0, st);
    tp< 64,  64,  64>(wb + 10240, tw2, i0, st);
    tp< 32,  64,  64>(wb + 14336, tw3, i0, st);
    tp<128, 128, 108>(wb + 16384, mw1, i0, st);
    tp<128, 128, 128>(wb + 32768, mw2, i0, st);
    tp< 64, 128, 128>(wb + 49152, mw3, i0, st);
}

// ---------------------------------------------------------------------------
// Fused MFMA set encoder (robot + track in one dispatch).
// Weights staged once into LDS; L1 B-frags built directly from global X
// (only qd==0 lanes carry nonzero k), so no X staging / zero-pad at all.
// hs: h1 -> h2 -> e3(f32), wave-private until pre-pool barrier.
// ---------------------------------------------------------------------------
struct EncSmem {
    __bf16 hs[128 * 72];     // 18432 B: h1/h2, then e3 = f32 [128][36]
    __bf16 w1[64 * 40];      // 5120 B
    __bf16 w2[64 * 72];      // 9216 B
    __bf16 w3[32 * 72];      // 4608 B
    float  bs[160];          // b1|b2|b3
};

template<int DIN, int S>
DEV_INLINE void enc_body(EncSmem& sm, const float* __restrict__ X,
                         const __bf16* __restrict__ wenc,
                         const float* __restrict__ b1, const float* __restrict__ b2,
                         const float* __restrict__ b3,
                         __bf16* __restrict__ out, int bid)
{
    constexpr int NB = 128 / S;
    const int tid = threadIdx.x;
    const int w   = tid >> 6;
    const int l64 = tid & 63;
    const int ln  = l64 & 15;
    const int qd  = l64 >> 4;
    float* e3   = (float*)sm.hs;
    float* pool = (float*)sm.w1;     // w1 dead after L1; pool used after barrier

    // ---- stage weights ----
    {
        const uint4* wsrc = (const uint4*)wenc;   // [wt1 256 | wt2 512 | wt3 256]
        {
            int i = tid, r = i >> 2, c = i & 3;
            *(uint4*)&sm.w1[r * 40 + c * 8] = wsrc[i];
        }
        for (int i = tid; i < 512; i += 256) {
            int r = i >> 3, c = i & 7;
            *(uint4*)&sm.w2[r * 72 + c * 8] = wsrc[256 + i];
        }
        {
            int i = tid, r = i >> 3, c = i & 7;
            *(uint4*)&sm.w3[r * 72 + c * 8] = wsrc[768 + i];
        }
        if (tid < 160)
            sm.bs[tid] = (tid < 64) ? b1[tid]
                       : (tid < 128) ? b2[tid - 64] : b3[tid - 128];
    }
    __syncthreads();

    // ---- L1: K=32 (k>=DIN zero) -> 64; x loaded directly from global ----
    {
        bf16x8 xb[2];
#pragma unroll
        for (int t = 0; t < 2; ++t) {
            bf16x8 v;
#pragma unroll
            for (int j = 0; j < 8; ++j) v[j] = (__bf16)0.0f;
            if (qd == 0) {
                const int row = (2 * w + t) * 16 + ln;
                const float* xp = X + ((size_t)bid * 128 + row) * DIN;
#pragma unroll
                for (int j = 0; j < DIN; ++j) v[j] = (__bf16)xp[j];
            }
            xb[t] = v;
        }
#pragma unroll
        for (int mt = 0; mt < 4; ++mt) {
            bf16x8 af = ld_frag(&sm.w1[(mt * 16 + ln) * 40 + qd * 8]);
            float4 bv = *(const float4*)&sm.bs[mt * 16 + qd * 4];
#pragma unroll
            for (int t = 0; t < 2; ++t) {
                floatx4 acc = (floatx4){bv.x, bv.y, bv.z, bv.w};
                acc = __builtin_amdgcn_mfma_f32_16x16x32_bf16(af, xb[t], acc, 0, 0, 0);
                st4_relu(&sm.hs[((2 * w + t) * 16 + ln) * 72 + mt * 16 + qd * 4], acc);
            }
        }
    }

    // ---- L2: 64 -> 64 ----
    {
        bf16x8 bfr[2][2];
#pragma unroll
        for (int t = 0; t < 2; ++t)
#pragma unroll
            for (int kq = 0; kq < 2; ++kq)
                bfr[t][kq] = ld_frag(&sm.hs[((2 * w + t) * 16 + ln) * 72 + kq * 32 + qd * 8]);
        MEM_FENCE;
#pragma unroll
        for (int mt = 0; mt < 4; ++mt) {
            bf16x8 a0 = ld_frag(&sm.w2[(mt * 16 + ln) * 72 + qd * 8]);
            bf16x8 a1 = ld_frag(&sm.w2[(mt * 16 + ln) * 72 + 32 + qd * 8]);
            float4 bv = *(const float4*)&sm.bs[64 + mt * 16 + qd * 4];
#pragma unroll
            for (int t = 0; t < 2; ++t) {
                floatx4 acc = (floatx4){bv.x, bv.y, bv.z, bv.w};
                acc = __builtin_amdgcn_mfma_f32_16x16x32_bf16(a0, bfr[t][0], acc, 0, 0, 0);
                acc = __builtin_amdgcn_mfma_f32_16x16x32_bf16(a1, bfr[t][1], acc, 0, 0, 0);
                st4_relu(&sm.hs[((2 * w + t) * 16 + ln) * 72 + mt * 16 + qd * 4], acc);
            }
        }
    }

    // ---- L3: 64 -> 32, fp32 e3 overwrites hs ----
    {
        bf16x8 bfr[2][2];
#pragma unroll
        for (int t = 0; t < 2; ++t)
#pragma unroll
            for (int kq = 0; kq < 2; ++kq)
                bfr[t][kq] = ld_frag(&sm.hs[((2 * w + t) * 16 + ln) * 72 + kq * 32 + qd * 8]);
        MEM_FENCE;
#pragma unroll
        for (int mt = 0; mt < 2; ++mt) {
            bf16x8 a0 = ld_frag(&sm.w3[(mt * 16 + ln) * 72 + qd * 8]);
            bf16x8 a1 = ld_frag(&sm.w3[(mt * 16 + ln) * 72 + 32 + qd * 8]);
            float4 bv = *(const float4*)&sm.bs[128 + mt * 16 + qd * 4];
#pragma unroll
            for (int t = 0; t < 2; ++t) {
                floatx4 acc = (floatx4){bv.x, bv.y, bv.z, bv.w};
                acc = __builtin_amdgcn_mfma_f32_16x16x32_bf16(a0, bfr[t][0], acc, 0, 0, 0);
                acc = __builtin_amdgcn_mfma_f32_16x16x32_bf16(a1, bfr[t][1], acc, 0, 0, 0);
                float4 o = {acc[0], acc[1], acc[2], acc[3]};
                *(float4*)&e3[((2 * w + t) * 16 + ln) * 36 + mt * 16 + qd * 4] = o;
            }
        }
    }
    __syncthreads();

    // ---- pool (mean+max)/2 over S rows per batch ----
    {
        const int o  = tid & 31;
        const int bi = (tid >> 5) % NB;
        const int ch = tid / (32 * NB);
        float s = 0.0f, m = -3.4e38f;
#pragma unroll
        for (int r = 0; r < 16; ++r) {
            float v = e3[(bi * S + ch * 16 + r) * 36 + o];
            s += v;
            m = fmaxf(m, v);
        }
        pool[tid] = s;
        pool[256 + tid] = m;
    }
    __syncthreads();
    if (tid < NB * 32) {
        constexpr int C = 8 / NB;
        float s = 0.0f, m = -3.4e38f;
#pragma unroll
        for (int c = 0; c < C; ++c) {
            s += pool[tid + c * 32 * NB];
            m = fmaxf(m, pool[256 + tid + c * 32 * NB]);
        }
        size_t b = (size_t)bid * NB + (tid >> 5);
        out[b * 32 + (tid & 31)] = (__bf16)(0.5f * (s * (1.0f / S) + m));
    }
}

__global__ __launch_bounds__(256)
void enc_fused(const float* __restrict__ rX, const float* __restrict__ tX,
               const __bf16* __restrict__ wb,
               const float* __restrict__ rb1, const float* __restrict__ rb2,
               const float* __restrict__ rb3,
               const float* __restrict__ tb1, const float* __restrict__ tb2,
               const float* __restrict__ tb3,
               __bf16* __restrict__ remb, __bf16* __restrict__ temb, int nr)
{
    __shared__ EncSmem sm;
    if ((int)blockIdx.x < nr)
        enc_body<6, 64>(sm, rX, wb, rb1, rb2, rb3, remb, blockIdx.x);
    else
        enc_body<7, 128>(sm, tX, wb + 8192, tb1, tb2, tb3, temb, blockIdx.x - nr);
}

// ---------------------------------------------------------------------------
// Head: 16 rows/block (1024 blocks -> 4 blocks/CU), m-split across 4 waves.
// concat[108 pad 128] -> 128 -> 128 -> 64 (MFMA bf16) -> 1 (fp32, wave 0).
// ---------------------------------------------------------------------------
__global__ __launch_bounds__(256)
void head_mfma(const float* __restrict__ t0,
               const __bf16* __restrict__ remb, const __bf16* __restrict__ temb,
               const __bf16* __restrict__ hw1, const float* __restrict__ b1,
               const __bf16* __restrict__ hw2, const float* __restrict__ b2,
               const __bf16* __restrict__ hw3, const float* __restrict__ b3,
               const float* __restrict__ w4, const float* __restrict__ b4,
               float* __restrict__ out)
{
    __shared__ __align__(16) __bf16 cb[16 * 136];   // c, then h2
    __shared__ __align__(16) __bf16 hb[16 * 136];   // h1
    __shared__ __align__(16) __bf16 h3[16 * 72];

    const int tid = threadIdx.x;
    const int w   = tid >> 6;
    const int l64 = tid & 63;
    const int ln  = l64 & 15;
    const int qd  = l64 >> 4;
    const int g0  = blockIdx.x * 16;

    // ---- stage c[108] = [tier0(44)|remb(32)|temb(32)] + pad ----
    for (int i = tid; i < 16 * 44; i += 256) {
        int r = i / 44, k = i - r * 44;
        cb[r * 136 + k] = (__bf16)t0[(size_t)(g0 + r) * 44 + k];
    }
    for (int i = tid; i < 16 * 32; i += 256) {
        int r = i >> 5, k = i & 31;
        cb[r * 136 + 44 + k] = remb[(size_t)(g0 + r) * 32 + k];
        cb[r * 136 + 76 + k] = temb[(size_t)(g0 + r) * 32 + k];
    }
    for (int i = tid; i < 16 * 20; i += 256) {
        int r = i / 20, k = i - r * 20;
        cb[r * 136 + 108 + k] = (__bf16)0.0f;
    }
    __syncthreads();

    // ---- L1: 128-pad -> 128, wave w owns m-tiles {2w, 2w+1} ----
    {
        bf16x8 bfr[4];
#pragma unroll
        for (int kq = 0; kq < 4; ++kq)
            bfr[kq] = ld_frag(&cb[ln * 136 + kq * 32 + qd * 8]);
#pragma unroll
        for (int m2 = 0; m2 < 2; ++m2) {
            int mt = 2 * w + m2;
            bf16x8 af[4];
#pragma unroll
            for (int kq = 0; kq < 4; ++kq)
                af[kq] = ld_frag(&hw1[(mt * 16 + ln) * 128 + kq * 32 + qd * 8]);
            float4 bv = *(const float4*)&b1[mt * 16 + qd * 4];
            floatx4 acc = (floatx4){bv.x, bv.y, bv.z, bv.w};
#pragma unroll
            for (int kq = 0; kq < 4; ++kq)
                acc = __builtin_amdgcn_mfma_f32_16x16x32_bf16(af[kq], bfr[kq], acc, 0, 0, 0);
            st4_relu(&hb[ln * 136 + mt * 16 + qd * 4], acc);
        }
    }
    __syncthreads();

    // ---- L2: 128 -> 128 (hb -> cb) ----
    {
        bf16x8 bfr[4];
#pragma unroll
        for (int kq = 0; kq < 4; ++kq)
            bfr[kq] = ld_frag(&hb[ln * 136 + kq * 32 + qd * 8]);
#pragma unroll
        for (int m2 = 0; m2 < 2; ++m2) {
            int mt = 2 * w + m2;
            bf16x8 af[4];
#pragma unroll
            for (int kq = 0; kq < 4; ++kq)
                af[kq] = ld_frag(&hw2[(mt * 16 + ln) * 128 + kq * 32 + qd * 8]);
            float4 bv = *(const float4*)&b2[mt * 16 + qd * 4];
            floatx4 acc = (floatx4){bv.x, bv.y, bv.z, bv.w};
#pragma unroll
            for (int kq = 0; kq < 4; ++kq)
                acc = __builtin_amdgcn_mfma_f32_16x16x32_bf16(af[kq], bfr[kq], acc, 0, 0, 0);
            st4_relu(&cb[ln * 136 + mt * 16 + qd * 4], acc);
        }
    }
    __syncthreads();

    // ---- L3: 128 -> 64, wave w owns m-tile w ----
    {
        bf16x8 bfr[4];
#pragma unroll
        for (int kq = 0; kq < 4; ++kq)
            bfr[kq] = ld_frag(&cb[ln * 136 + kq * 32 + qd * 8]);
        bf16x8 af[4];
#pragma unroll
        for (int kq = 0; kq < 4; ++kq)
            af[kq] = ld_frag(&hw3[(w * 16 + ln) * 128 + kq * 32 + qd * 8]);
        float4 bv = *(const float4*)&b3[w * 16 + qd * 4];
        floatx4 acc = (floatx4){bv.x, bv.y, bv.z, bv.w};
#pragma unroll
        for (int kq = 0; kq < 4; ++kq)
            acc = __builtin_amdgcn_mfma_f32_16x16x32_bf16(af[kq], bfr[kq], acc, 0, 0, 0);
        st4_relu(&h3[ln * 72 + w * 16 + qd * 4], acc);
    }
    __syncthreads();

    // ---- L4: 64 -> 1 fp32, wave 0 only; lane (ln,qd): row ln, k-slice qd ----
    if (w == 0) {
        float part = 0.0f;
#pragma unroll
        for (int c = 0; c < 2; ++c) {
            bf16x8 hv = ld_frag(&h3[ln * 72 + qd * 16 + c * 8]);
#pragma unroll
            for (int u = 0; u < 8; ++u)
                part = fmaf((float)hv[u], w4[qd * 16 + c * 8 + u], part);
        }
        part += __shfl_xor(part, 16);
        part += __shfl_xor(part, 32);
        if (qd == 0)
            out[g0 + ln] = part + b4[0];
    }
}

extern "C" void kernel_launch(void* const* d_in, const int* in_sizes, int n_in,
                              void* d_out, int out_size, void* d_ws, size_t ws_size,
                              hipStream_t stream)
{
    const float* t0  = (const float*)d_in[0];
    const float* rX  = (const float*)d_in[1];
    const float* tX  = (const float*)d_in[2];
    const float* rw1 = (const float*)d_in[3];  const float* rb1 = (const float*)d_in[4];
    const float* rw2 = (const float*)d_in[5];  const float* rb2 = (const float*)d_in[6];
    const float* rw3 = (const float*)d_in[7];  const float* rb3 = (const float*)d_in[8];
    const float* tw1 = (const float*)d_in[9];  const float* tb1 = (const float*)d_in[10];
    const float* tw2 = (const float*)d_in[11]; const float* tb2 = (const float*)d_in[12];
    const float* tw3 = (const float*)d_in[13]; const float* tb3 = (const float*)d_in[14];
    const float* mw1 = (const float*)d_in[15]; const float* mb1 = (const float*)d_in[16];
    const float* mw2 = (const float*)d_in[17]; const float* mb2 = (const float*)d_in[18];
    const float* mw3 = (const float*)d_in[19]; const float* mb3 = (const float*)d_in[20];
    const float* mw4 = (const float*)d_in[21]; const float* mb4 = (const float*)d_in[22];
    float* out = (float*)d_out;

    const int B = 16384;
    __bf16* remb = (__bf16*)d_ws;
    __bf16* temb = (__bf16*)((char*)d_ws + ((size_t)1 << 20));
    __bf16* wb   = (__bf16*)((char*)d_ws + ((size_t)2 << 20));
    const __bf16* mw1b = wb + 16384; const __bf16* mw2b = wb + 32768;
    const __bf16* mw3b = wb + 49152;

    prep_kernel<<<64, 256, 0, stream>>>(rw1, rw2, rw3, tw1, tw2, tw3,
                                        mw1, mw2, mw3, wb);
    const int nr = (B * 64) / 128;                       // 8192 robot blocks
    const int nt = (B * 128) / 128;                      // 16384 track blocks
    enc_fused<<<nr + nt, 256, 0, stream>>>(rX, tX, wb,
                                           rb1, rb2, rb3, tb1, tb2, tb3,
                                           remb, temb, nr);
    head_mfma<<<B / 16, 256, 0, stream>>>(t0, remb, temb,
                                          mw1b, mb1, mw2b, mb2, mw3b, mb3,
                                          mw4, mb4, out);
}

// Round 7
// 252.527 us; speedup vs baseline: 1.3694x; 1.0882x over previous
//
#include <hip/hip_runtime.h>
#include <hip/hip_bf16.h>

#define DEV_INLINE __device__ __forceinline__
#define MEM_FENCE asm volatile("" ::: "memory")

typedef __bf16 bf16x8 __attribute__((ext_vector_type(8)));
typedef float  floatx4 __attribute__((ext_vector_type(4)));

DEV_INLINE bf16x8 ld_frag(const __bf16* p) {
    union { uint4 u; bf16x8 v; } t;
    t.u = *(const uint4*)p;
    return t.v;
}
// relu + pack two f32x4 accumulators into the next layer's B-fragment.
// Element j of the frag = relu(acc[2kq + (j>>2)][j&3]) -> matches the k-perm
// used in prep (tp_perm): feat(k_hw) = (2*kq + (j>>2))*16 + qd*4 + (j&3).
DEV_INLINE bf16x8 pack_relu2(floatx4 a, floatx4 b) {
    float2 p0 = {fmaxf(a[0], 0.0f), fmaxf(a[1], 0.0f)};
    float2 p1 = {fmaxf(a[2], 0.0f), fmaxf(a[3], 0.0f)};
    float2 p2 = {fmaxf(b[0], 0.0f), fmaxf(b[1], 0.0f)};
    float2 p3 = {fmaxf(b[2], 0.0f), fmaxf(b[3], 0.0f)};
    union { __hip_bfloat162 h[4]; bf16x8 v; } t;
    t.h[0] = __float22bfloat162_rn(p0);
    t.h[1] = __float22bfloat162_rn(p1);
    t.h[2] = __float22bfloat162_rn(p2);
    t.h[3] = __float22bfloat162_rn(p3);
    return t.v;
}
DEV_INLINE floatx4 vmax4(floatx4 a, floatx4 b) {
    floatx4 r;
#pragma unroll
    for (int i = 0; i < 4; ++i) r[i] = fmaxf(a[i], b[i]);
    return r;
}

// ---------------------------------------------------------------------------
// Prep. tp: natural transpose+pad (A-layout [n][k], k contiguous).
// tp_perm: k-permuted transpose so the consumer can use the previous layer's
// accumulator registers directly as its B operand.
// ---------------------------------------------------------------------------
template<int N, int Kp, int Ks>
DEV_INLINE void tp(__bf16* dst, const float* __restrict__ src, int idx0, int stride) {
    for (int e = idx0; e < N * Kp; e += stride) {
        int n = e / Kp, k = e - n * Kp;
        dst[e] = (k < Ks) ? (__bf16)src[k * N + n] : (__bf16)0.0f;
    }
}
template<int N, int K>   // dst[n][k_hw] = src[c(k_hw)][n]
DEV_INLINE void tp_perm(__bf16* dst, const float* __restrict__ src, int idx0, int stride) {
    for (int e = idx0; e < N * K; e += stride) {
        int n = e / K, kh = e - n * K;
        int qd = (kh >> 3) & 3, kq = kh >> 5, j = kh & 7;
        int c = (2 * kq + (j >> 2)) * 16 + qd * 4 + (j & 3);
        dst[e] = (__bf16)src[c * N + n];
    }
}

__global__ __launch_bounds__(256)
void prep_kernel(const float* __restrict__ rw1, const float* __restrict__ rw2,
                 const float* __restrict__ rw3,
                 const float* __restrict__ tw1, const float* __restrict__ tw2,
                 const float* __restrict__ tw3,
                 const float* __restrict__ mw1, const float* __restrict__ mw2,
                 const float* __restrict__ mw3, __bf16* __restrict__ wb)
{
    int i0 = blockIdx.x * 256 + threadIdx.x;
    int st = gridDim.x * 256;
    tp     < 64,  32,   6>(wb + 0,     rw1, i0, st);
    tp_perm< 64,  64>     (wb + 2048,  rw2, i0, st);
    tp_perm< 32,  64>     (wb + 6144,  rw3, i0, st);
    tp     < 64,  32,   7>(wb + 8192,  tw1, i0, st);
    tp_perm< 64,  64>     (wb + 10240, tw2, i0, st);
    tp_perm< 32,  64>     (wb + 14336, tw3, i0, st);
    tp     <128, 128, 108>(wb + 16384, mw1, i0, st);
    tp_perm<128, 128>     (wb + 32768, mw2, i0, st);
    tp_perm< 64, 128>     (wb + 49152, mw3, i0, st);
}

// ---------------------------------------------------------------------------
// Fused MFMA set encoder: L1->L2->L3 fully register-resident per wave.
// Only LDS: staged weights + the pooled partials (e3s/e3m).
// ---------------------------------------------------------------------------
struct __align__(16) EncSmem {
    float  e3s[64 * 36];     // per part-row (w*16+ln) partial sums   9216 B
    float  e3m[64 * 36];     // partial maxes                          9216 B
    __bf16 w1[64 * 40];      // 5120 B (pool aliases this after L1)
    __bf16 w2[64 * 72];      // 9216 B
    __bf16 w3[32 * 72];      // 4608 B
    float  bs[160];          // b1|b2|b3
};

template<int DIN, int S>
DEV_INLINE void enc_body(EncSmem& sm, const float* __restrict__ X,
                         const __bf16* __restrict__ wenc,
                         const float* __restrict__ b1, const float* __restrict__ b2,
                         const float* __restrict__ b3,
                         __bf16* __restrict__ out, int bid)
{
    constexpr int NB = 128 / S;
    const int tid = threadIdx.x;
    const int w   = tid >> 6;
    const int l64 = tid & 63;
    const int ln  = l64 & 15;
    const int qd  = l64 >> 4;
    float* pool = (float*)sm.w1;   // dead after L1; used after barrier

    // ---- stage weights ----
    {
        const uint4* wsrc = (const uint4*)wenc;   // [wt1 256 | wt2 512 | wt3 256]
        { int i = tid, r = i >> 2, c = i & 3;  *(uint4*)&sm.w1[r * 40 + c * 8] = wsrc[i]; }
        for (int i = tid; i < 512; i += 256) {
            int r = i >> 3, c = i & 7;  *(uint4*)&sm.w2[r * 72 + c * 8] = wsrc[256 + i];
        }
        { int i = tid, r = i >> 3, c = i & 7;  *(uint4*)&sm.w3[r * 72 + c * 8] = wsrc[768 + i]; }
        if (tid < 160)
            sm.bs[tid] = (tid < 64) ? b1[tid]
                       : (tid < 128) ? b2[tid - 64] : b3[tid - 128];
    }
    __syncthreads();

    // ---- L1: K=32 (weights zero for k>=DIN); x direct from global ----
    bf16x8 xb[2];
#pragma unroll
    for (int t = 0; t < 2; ++t) {
        bf16x8 v;
#pragma unroll
        for (int j = 0; j < 8; ++j) v[j] = (__bf16)0.0f;
        if (qd == 0) {
            const int row = (2 * w + t) * 16 + ln;
            const float* xp = X + ((size_t)bid * 128 + row) * DIN;
#pragma unroll
            for (int j = 0; j < DIN; ++j) v[j] = (__bf16)xp[j];
        }
        xb[t] = v;
    }
    floatx4 a1[2][4];
#pragma unroll
    for (int mt = 0; mt < 4; ++mt) {
        bf16x8 af = ld_frag(&sm.w1[(mt * 16 + ln) * 40 + qd * 8]);
        float4 bv = *(const float4*)&sm.bs[mt * 16 + qd * 4];
#pragma unroll
        for (int t = 0; t < 2; ++t) {
            floatx4 acc = (floatx4){bv.x, bv.y, bv.z, bv.w};
            a1[t][mt] = __builtin_amdgcn_mfma_f32_16x16x32_bf16(af, xb[t], acc, 0, 0, 0);
        }
    }
    // ---- relu+pack: a1 -> L2 B-frags (k-perm consistent with tp_perm) ----
    bf16x8 f1[2][2];
#pragma unroll
    for (int t = 0; t < 2; ++t)
#pragma unroll
        for (int kq = 0; kq < 2; ++kq)
            f1[t][kq] = pack_relu2(a1[t][2 * kq], a1[t][2 * kq + 1]);

    // ---- L2: 64 -> 64 ----
    floatx4 a2[2][4];
#pragma unroll
    for (int mt = 0; mt < 4; ++mt) {
        bf16x8 a0 = ld_frag(&sm.w2[(mt * 16 + ln) * 72 + qd * 8]);
        bf16x8 a1f = ld_frag(&sm.w2[(mt * 16 + ln) * 72 + 32 + qd * 8]);
        float4 bv = *(const float4*)&sm.bs[64 + mt * 16 + qd * 4];
#pragma unroll
        for (int t = 0; t < 2; ++t) {
            floatx4 acc = (floatx4){bv.x, bv.y, bv.z, bv.w};
            acc = __builtin_amdgcn_mfma_f32_16x16x32_bf16(a0, f1[t][0], acc, 0, 0, 0);
            acc = __builtin_amdgcn_mfma_f32_16x16x32_bf16(a1f, f1[t][1], acc, 0, 0, 0);
            a2[t][mt] = acc;
        }
    }
    bf16x8 f2[2][2];
#pragma unroll
    for (int t = 0; t < 2; ++t)
#pragma unroll
        for (int kq = 0; kq < 2; ++kq)
            f2[t][kq] = pack_relu2(a2[t][2 * kq], a2[t][2 * kq + 1]);

    // ---- L3: 64 -> 32 (fp32 out, stays in regs) ----
    floatx4 a3[2][2];
#pragma unroll
    for (int mt = 0; mt < 2; ++mt) {
        bf16x8 a0 = ld_frag(&sm.w3[(mt * 16 + ln) * 72 + qd * 8]);
        bf16x8 a1f = ld_frag(&sm.w3[(mt * 16 + ln) * 72 + 32 + qd * 8]);
        float4 bv = *(const float4*)&sm.bs[128 + mt * 16 + qd * 4];
#pragma unroll
        for (int t = 0; t < 2; ++t) {
            floatx4 acc = (floatx4){bv.x, bv.y, bv.z, bv.w};
            acc = __builtin_amdgcn_mfma_f32_16x16x32_bf16(a0, f2[t][0], acc, 0, 0, 0);
            acc = __builtin_amdgcn_mfma_f32_16x16x32_bf16(a1f, f2[t][1], acc, 0, 0, 0);
            a3[t][mt] = acc;
        }
    }
    // ---- in-register t-combine, then partial store for pooling ----
#pragma unroll
    for (int mt = 0; mt < 2; ++mt) {
        floatx4 s = a3[0][mt] + a3[1][mt];
        floatx4 m = vmax4(a3[0][mt], a3[1][mt]);
        float4 so = {s[0], s[1], s[2], s[3]};
        float4 mo = {m[0], m[1], m[2], m[3]};
        *(float4*)&sm.e3s[(w * 16 + ln) * 36 + mt * 16 + qd * 4] = so;
        *(float4*)&sm.e3m[(w * 16 + ln) * 36 + mt * 16 + qd * 4] = mo;
    }
    __syncthreads();

    // ---- pool (mean+max)/2; 64 part-rows (each covers 2 element-rows) ----
    {
        constexpr int R = 64 / NB;               // part-rows per batch
        const int o  = tid & 31;
        const int bi = (tid >> 5) % NB;
        const int ch = tid / (32 * NB);          // 8/NB chunks of 8 part-rows
        const int p0 = bi * R + ch * 8;
        float s = 0.0f, m = -3.4e38f;
#pragma unroll
        for (int r = 0; r < 8; ++r) {
            s += sm.e3s[(p0 + r) * 36 + o];
            m = fmaxf(m, sm.e3m[(p0 + r) * 36 + o]);
        }
        pool[tid] = s;
        pool[256 + tid] = m;
    }
    __syncthreads();
    if (tid < NB * 32) {
        constexpr int C = 8 / NB;
        float s = 0.0f, m = -3.4e38f;
#pragma unroll
        for (int c = 0; c < C; ++c) {
            s += pool[tid + c * 32 * NB];
            m = fmaxf(m, pool[256 + tid + c * 32 * NB]);
        }
        size_t b = (size_t)bid * NB + (tid >> 5);
        out[b * 32 + (tid & 31)] = (__bf16)(0.5f * (s * (1.0f / S) + m));
    }
}

__global__ __launch_bounds__(256)
void enc_fused(const float* __restrict__ rX, const float* __restrict__ tX,
               const __bf16* __restrict__ wb,
               const float* __restrict__ rb1, const float* __restrict__ rb2,
               const float* __restrict__ rb3,
               const float* __restrict__ tb1, const float* __restrict__ tb2,
               const float* __restrict__ tb3,
               __bf16* __restrict__ remb, __bf16* __restrict__ temb, int nr)
{
    __shared__ EncSmem sm;
    if ((int)blockIdx.x < nr)
        enc_body<6, 64>(sm, rX, wb, rb1, rb2, rb3, remb, blockIdx.x);
    else
        enc_body<7, 128>(sm, tX, wb + 8192, tb1, tb2, tb3, temb, blockIdx.x - nr);
}

// ---------------------------------------------------------------------------
// Head, register-chained: stage c (1 barrier), then L1->L2->L3->dot all in
// regs per wave (16 rows). hw2/hw3 are k-permuted; hw1/b*/w4 natural.
// ---------------------------------------------------------------------------
__global__ __launch_bounds__(256)
void head_mfma(const float* __restrict__ t0,
               const __bf16* __restrict__ remb, const __bf16* __restrict__ temb,
               const __bf16* __restrict__ hw1, const float* __restrict__ b1,
               const __bf16* __restrict__ hw2, const float* __restrict__ b2,
               const __bf16* __restrict__ hw3, const float* __restrict__ b3,
               const float* __restrict__ w4, const float* __restrict__ b4,
               float* __restrict__ out)
{
    __shared__ __align__(16) __bf16 cb[64 * 136];

    const int tid = threadIdx.x;
    const int w   = tid >> 6;
    const int l64 = tid & 63;
    const int ln  = l64 & 15;
    const int qd  = l64 >> 4;
    const int g0  = blockIdx.x * 64;

    // ---- stage c[108] = [tier0(44)|remb(32)|temb(32)] + pad to 128 ----
    for (int i = tid; i < 64 * 44; i += 256) {
        int r = i / 44, k = i - r * 44;
        cb[r * 136 + k] = (__bf16)t0[(size_t)(g0 + r) * 44 + k];
    }
    for (int i = tid; i < 64 * 32; i += 256) {
        int r = i >> 5, k = i & 31;
        cb[r * 136 + 44 + k] = remb[(size_t)(g0 + r) * 32 + k];
        cb[r * 136 + 76 + k] = temb[(size_t)(g0 + r) * 32 + k];
    }
    for (int i = tid; i < 64 * 20; i += 256) {
        int r = i / 20, k = i - r * 20;
        cb[r * 136 + 108 + k] = (__bf16)0.0f;
    }
    __syncthreads();

    // ---- L1: 128-pad -> 128 ----
    bf16x8 cf[4];
#pragma unroll
    for (int kq = 0; kq < 4; ++kq)
        cf[kq] = ld_frag(&cb[(w * 16 + ln) * 136 + kq * 32 + qd * 8]);
    floatx4 acc1[8];
#pragma unroll
    for (int mt = 0; mt < 8; ++mt) {
        float4 bv = *(const float4*)&b1[mt * 16 + qd * 4];
        floatx4 acc = (floatx4){bv.x, bv.y, bv.z, bv.w};
#pragma unroll
        for (int kq = 0; kq < 4; ++kq) {
            bf16x8 af = ld_frag(&hw1[(mt * 16 + ln) * 128 + kq * 32 + qd * 8]);
            acc = __builtin_amdgcn_mfma_f32_16x16x32_bf16(af, cf[kq], acc, 0, 0, 0);
        }
        acc1[mt] = acc;
    }
    bf16x8 f1[4];
#pragma unroll
    for (int kq = 0; kq < 4; ++kq)
        f1[kq] = pack_relu2(acc1[2 * kq], acc1[2 * kq + 1]);

    // ---- L2: 128 -> 128 ----
    floatx4 acc2[8];
#pragma unroll
    for (int mt = 0; mt < 8; ++mt) {
        float4 bv = *(const float4*)&b2[mt * 16 + qd * 4];
        floatx4 acc = (floatx4){bv.x, bv.y, bv.z, bv.w};
#pragma unroll
        for (int kq = 0; kq < 4; ++kq) {
            bf16x8 af = ld_frag(&hw2[(mt * 16 + ln) * 128 + kq * 32 + qd * 8]);
            acc = __builtin_amdgcn_mfma_f32_16x16x32_bf16(af, f1[kq], acc, 0, 0, 0);
        }
        acc2[mt] = acc;
    }
    bf16x8 f2[4];
#pragma unroll
    for (int kq = 0; kq < 4; ++kq)
        f2[kq] = pack_relu2(acc2[2 * kq], acc2[2 * kq + 1]);

    // ---- L3: 128 -> 64 ----
    floatx4 acc3[4];
#pragma unroll
    for (int mt = 0; mt < 4; ++mt) {
        float4 bv = *(const float4*)&b3[mt * 16 + qd * 4];
        floatx4 acc = (floatx4){bv.x, bv.y, bv.z, bv.w};
#pragma unroll
        for (int kq = 0; kq < 4; ++kq) {
            bf16x8 af = ld_frag(&hw3[(mt * 16 + ln) * 128 + kq * 32 + qd * 8]);
            acc = __builtin_amdgcn_mfma_f32_16x16x32_bf16(af, f2[kq], acc, 0, 0, 0);
        }
        acc3[mt] = acc;
    }

    // ---- L4: 64 -> 1 fp32; lane holds feats mt*16+qd*4+rg of row ln ----
    float part = 0.0f;
#pragma unroll
    for (int mt = 0; mt < 4; ++mt) {
        float4 wv = *(const float4*)&w4[mt * 16 + qd * 4];
        part = fmaf(fmaxf(acc3[mt][0], 0.0f), wv.x, part);
        part = fmaf(fmaxf(acc3[mt][1], 0.0f), wv.y, part);
        part = fmaf(fmaxf(acc3[mt][2], 0.0f), wv.z, part);
        part = fmaf(fmaxf(acc3[mt][3], 0.0f), wv.w, part);
    }
    part += __shfl_xor(part, 16);
    part += __shfl_xor(part, 32);
    if (qd == 0)
        out[g0 + w * 16 + ln] = part + b4[0];
}

extern "C" void kernel_launch(void* const* d_in, const int* in_sizes, int n_in,
                              void* d_out, int out_size, void* d_ws, size_t ws_size,
                              hipStream_t stream)
{
    const float* t0  = (const float*)d_in[0];
    const float* rX  = (const float*)d_in[1];
    const float* tX  = (const float*)d_in[2];
    const float* rw1 = (const float*)d_in[3];  const float* rb1 = (const float*)d_in[4];
    const float* rw2 = (const float*)d_in[5];  const float* rb2 = (const float*)d_in[6];
    const float* rw3 = (const float*)d_in[7];  const float* rb3 = (const float*)d_in[8];
    const float* tw1 = (const float*)d_in[9];  const float* tb1 = (const float*)d_in[10];
    const float* tw2 = (const float*)d_in[11]; const float* tb2 = (const float*)d_in[12];
    const float* tw3 = (const float*)d_in[13]; const float* tb3 = (const float*)d_in[14];
    const float* mw1 = (const float*)d_in[15]; const float* mb1 = (const float*)d_in[16];
    const float* mw2 = (const float*)d_in[17]; const float* mb2 = (const float*)d_in[18];
    const float* mw3 = (const float*)d_in[19]; const float* mb3 = (const float*)d_in[20];
    const float* mw4 = (const float*)d_in[21]; const float* mb4 = (const float*)d_in[22];
    float* out = (float*)d_out;

    const int B = 16384;
    __bf16* remb = (__bf16*)d_ws;
    __bf16* temb = (__bf16*)((char*)d_ws + ((size_t)1 << 20));
    __bf16* wb   = (__bf16*)((char*)d_ws + ((size_t)2 << 20));
    const __bf16* mw1b = wb + 16384; const __bf16* mw2b = wb + 32768;
    const __bf16* mw3b = wb + 49152;

    prep_kernel<<<64, 256, 0, stream>>>(rw1, rw2, rw3, tw1, tw2, tw3,
                                        mw1, mw2, mw3, wb);
    const int nr = (B * 64) / 128;                       // 8192 robot blocks
    const int nt = (B * 128) / 128;                      // 16384 track blocks
    enc_fused<<<nr + nt, 256, 0, stream>>>(rX, tX, wb,
                                           rb1, rb2, rb3, tb1, tb2, tb3,
                                           remb, temb, nr);
    head_mfma<<<B / 64, 256, 0, stream>>>(t0, remb, temb,
                                          mw1b, mb1, mw2b, mb2, mw3b, mb3,
                                          mw4, mb4, out);
}

// Round 8
// 238.629 us; speedup vs baseline: 1.4491x; 1.0582x over previous
//
#include <hip/hip_runtime.h>
#include <hip/hip_bf16.h>

#define DEV_INLINE __device__ __forceinline__

typedef __bf16 bf16x8 __attribute__((ext_vector_type(8)));
typedef float  floatx4 __attribute__((ext_vector_type(4)));

DEV_INLINE bf16x8 ld_frag(const __bf16* p) {
    union { uint4 u; bf16x8 v; } t;
    t.u = *(const uint4*)p;
    return t.v;
}
// relu + pack two f32x4 accumulators into the next layer's B-fragment.
// Element j of the frag = relu(acc[2kq + (j>>2)][j&3]) -> matches tp_perm:
// feat(k_hw) = (2*kq + (j>>2))*16 + qd*4 + (j&3).
DEV_INLINE bf16x8 pack_relu2(floatx4 a, floatx4 b) {
    float2 p0 = {fmaxf(a[0], 0.0f), fmaxf(a[1], 0.0f)};
    float2 p1 = {fmaxf(a[2], 0.0f), fmaxf(a[3], 0.0f)};
    float2 p2 = {fmaxf(b[0], 0.0f), fmaxf(b[1], 0.0f)};
    float2 p3 = {fmaxf(b[2], 0.0f), fmaxf(b[3], 0.0f)};
    union { __hip_bfloat162 h[4]; bf16x8 v; } t;
    t.h[0] = __float22bfloat162_rn(p0);
    t.h[1] = __float22bfloat162_rn(p1);
    t.h[2] = __float22bfloat162_rn(p2);
    t.h[3] = __float22bfloat162_rn(p3);
    return t.v;
}
DEV_INLINE floatx4 vmax4(floatx4 a, floatx4 b) {
    floatx4 r;
#pragma unroll
    for (int i = 0; i < 4; ++i) r[i] = fmaxf(a[i], b[i]);
    return r;
}

// ---------------------------------------------------------------------------
// Prep. tp: natural transpose+pad (A-layout [n][k]). tp_perm: k-permuted so
// the consumer uses the previous layer's accumulators directly as B operand.
// ---------------------------------------------------------------------------
template<int N, int Kp, int Ks>
DEV_INLINE void tp(__bf16* dst, const float* __restrict__ src, int idx0, int stride) {
    for (int e = idx0; e < N * Kp; e += stride) {
        int n = e / Kp, k = e - n * Kp;
        dst[e] = (k < Ks) ? (__bf16)src[k * N + n] : (__bf16)0.0f;
    }
}
template<int N, int K>   // dst[n][k_hw] = src[c(k_hw)][n]
DEV_INLINE void tp_perm(__bf16* dst, const float* __restrict__ src, int idx0, int stride) {
    for (int e = idx0; e < N * K; e += stride) {
        int n = e / K, kh = e - n * K;
        int qd = (kh >> 3) & 3, kq = kh >> 5, j = kh & 7;
        int c = (2 * kq + (j >> 2)) * 16 + qd * 4 + (j & 3);
        dst[e] = (__bf16)src[c * N + n];
    }
}

__global__ __launch_bounds__(256)
void prep_kernel(const float* __restrict__ rw1, const float* __restrict__ rw2,
                 const float* __restrict__ rw3,
                 const float* __restrict__ tw1, const float* __restrict__ tw2,
                 const float* __restrict__ tw3,
                 const float* __restrict__ mw1, const float* __restrict__ mw2,
                 const float* __restrict__ mw3, __bf16* __restrict__ wb)
{
    int i0 = blockIdx.x * 256 + threadIdx.x;
    int st = gridDim.x * 256;
    tp     < 64,  32,   6>(wb + 0,     rw1, i0, st);
    tp_perm< 64,  64>     (wb + 2048,  rw2, i0, st);
    tp_perm< 32,  64>     (wb + 6144,  rw3, i0, st);
    tp     < 64,  32,   7>(wb + 8192,  tw1, i0, st);
    tp_perm< 64,  64>     (wb + 10240, tw2, i0, st);
    tp_perm< 32,  64>     (wb + 14336, tw3, i0, st);
    tp     <128, 128, 108>(wb + 16384, mw1, i0, st);
    tp_perm<128, 128>     (wb + 32768, mw2, i0, st);
    tp_perm< 64, 128>     (wb + 49152, mw3, i0, st);
}

// ---------------------------------------------------------------------------
// Persistent fused encoder: 768 blocks (256 robot, 512 track), each loops
// over 32 row-blocks of 128 rows. Weight A-frags register-resident (loaded
// from global once per block); L1->L2->L3 register-chained; LDS only for
// biases + pooling partials. 21 KB LDS, __launch_bounds__(256,3).
// ---------------------------------------------------------------------------
struct __align__(16) EncSmem {
    float e3s[64 * 36];      // partial sums per part-row   9216 B
    float e3m[64 * 36];      // partial maxes               9216 B
    float pool[512];         // 2048 B
    float bs[160];           // b1|b2|b3
};

template<int DIN, int S, int ITERS>
DEV_INLINE void enc_loop(EncSmem& sm, const float* __restrict__ X,
                         const __bf16* __restrict__ w1p,
                         const __bf16* __restrict__ w2p,
                         const __bf16* __restrict__ w3p,
                         const float* __restrict__ b1, const float* __restrict__ b2,
                         const float* __restrict__ b3,
                         __bf16* __restrict__ out, int bid0)
{
    constexpr int NB = 128 / S;
    const int tid = threadIdx.x;
    const int w   = tid >> 6;
    const int l64 = tid & 63;
    const int ln  = l64 & 15;
    const int qd  = l64 >> 4;

    if (tid < 160)
        sm.bs[tid] = (tid < 64) ? b1[tid]
                   : (tid < 128) ? b2[tid - 64] : b3[tid - 128];

    // ---- weights -> registers, once per block (global, L2-resident) ----
    bf16x8 w1f[4], w2f[4][2], w3f[2][2];
#pragma unroll
    for (int mt = 0; mt < 4; ++mt)
        w1f[mt] = ld_frag(&w1p[(mt * 16 + ln) * 32 + qd * 8]);
#pragma unroll
    for (int mt = 0; mt < 4; ++mt)
#pragma unroll
        for (int kq = 0; kq < 2; ++kq)
            w2f[mt][kq] = ld_frag(&w2p[(mt * 16 + ln) * 64 + kq * 32 + qd * 8]);
#pragma unroll
    for (int mt = 0; mt < 2; ++mt)
#pragma unroll
        for (int kq = 0; kq < 2; ++kq)
            w3f[mt][kq] = ld_frag(&w3p[(mt * 16 + ln) * 64 + kq * 32 + qd * 8]);
    __syncthreads();

    for (int it = 0; it < ITERS; ++it) {
        const int bid = bid0 + it;

        // ---- L1: K=32 (weights zero-padded); x direct from global ----
        bf16x8 xb[2];
#pragma unroll
        for (int t = 0; t < 2; ++t) {
            bf16x8 v;
#pragma unroll
            for (int j = 0; j < 8; ++j) v[j] = (__bf16)0.0f;
            if (qd == 0) {
                const int row = (2 * w + t) * 16 + ln;
                const float* xp = X + ((size_t)bid * 128 + row) * DIN;
#pragma unroll
                for (int j = 0; j < DIN; ++j) v[j] = (__bf16)xp[j];
            }
            xb[t] = v;
        }
        floatx4 a1[2][4];
#pragma unroll
        for (int mt = 0; mt < 4; ++mt) {
            float4 bv = *(const float4*)&sm.bs[mt * 16 + qd * 4];
#pragma unroll
            for (int t = 0; t < 2; ++t) {
                floatx4 acc = (floatx4){bv.x, bv.y, bv.z, bv.w};
                a1[t][mt] = __builtin_amdgcn_mfma_f32_16x16x32_bf16(w1f[mt], xb[t], acc, 0, 0, 0);
            }
        }
        bf16x8 f1[2][2];
#pragma unroll
        for (int t = 0; t < 2; ++t)
#pragma unroll
            for (int kq = 0; kq < 2; ++kq)
                f1[t][kq] = pack_relu2(a1[t][2 * kq], a1[t][2 * kq + 1]);

        // ---- L2: 64 -> 64 ----
        floatx4 a2[2][4];
#pragma unroll
        for (int mt = 0; mt < 4; ++mt) {
            float4 bv = *(const float4*)&sm.bs[64 + mt * 16 + qd * 4];
#pragma unroll
            for (int t = 0; t < 2; ++t) {
                floatx4 acc = (floatx4){bv.x, bv.y, bv.z, bv.w};
                acc = __builtin_amdgcn_mfma_f32_16x16x32_bf16(w2f[mt][0], f1[t][0], acc, 0, 0, 0);
                acc = __builtin_amdgcn_mfma_f32_16x16x32_bf16(w2f[mt][1], f1[t][1], acc, 0, 0, 0);
                a2[t][mt] = acc;
            }
        }
        bf16x8 f2[2][2];
#pragma unroll
        for (int t = 0; t < 2; ++t)
#pragma unroll
            for (int kq = 0; kq < 2; ++kq)
                f2[t][kq] = pack_relu2(a2[t][2 * kq], a2[t][2 * kq + 1]);

        // ---- L3: 64 -> 32 (fp32, in regs) ----
        floatx4 a3[2][2];
#pragma unroll
        for (int mt = 0; mt < 2; ++mt) {
            float4 bv = *(const float4*)&sm.bs[128 + mt * 16 + qd * 4];
#pragma unroll
            for (int t = 0; t < 2; ++t) {
                floatx4 acc = (floatx4){bv.x, bv.y, bv.z, bv.w};
                acc = __builtin_amdgcn_mfma_f32_16x16x32_bf16(w3f[mt][0], f2[t][0], acc, 0, 0, 0);
                acc = __builtin_amdgcn_mfma_f32_16x16x32_bf16(w3f[mt][1], f2[t][1], acc, 0, 0, 0);
                a3[t][mt] = acc;
            }
        }
        // ---- in-register t-combine, store partials ----
#pragma unroll
        for (int mt = 0; mt < 2; ++mt) {
            floatx4 s = a3[0][mt] + a3[1][mt];
            floatx4 m = vmax4(a3[0][mt], a3[1][mt]);
            float4 so = {s[0], s[1], s[2], s[3]};
            float4 mo = {m[0], m[1], m[2], m[3]};
            *(float4*)&sm.e3s[(w * 16 + ln) * 36 + mt * 16 + qd * 4] = so;
            *(float4*)&sm.e3m[(w * 16 + ln) * 36 + mt * 16 + qd * 4] = mo;
        }
        __syncthreads();

        // ---- pool (mean+max)/2 over S rows per batch ----
        {
            constexpr int R = 64 / NB;
            const int o  = tid & 31;
            const int bi = (tid >> 5) % NB;
            const int ch = tid / (32 * NB);
            const int p0 = bi * R + ch * 8;
            float s = 0.0f, m = -3.4e38f;
#pragma unroll
            for (int r = 0; r < 8; ++r) {
                s += sm.e3s[(p0 + r) * 36 + o];
                m = fmaxf(m, sm.e3m[(p0 + r) * 36 + o]);
            }
            sm.pool[tid] = s;
            sm.pool[256 + tid] = m;
        }
        __syncthreads();
        if (tid < NB * 32) {
            constexpr int C = 8 / NB;
            float s = 0.0f, m = -3.4e38f;
#pragma unroll
            for (int c = 0; c < C; ++c) {
                s += sm.pool[tid + c * 32 * NB];
                m = fmaxf(m, sm.pool[256 + tid + c * 32 * NB]);
            }
            size_t b = (size_t)bid * NB + (tid >> 5);
            out[b * 32 + (tid & 31)] = (__bf16)(0.5f * (s * (1.0f / S) + m));
        }
    }
}

__global__ __launch_bounds__(256, 3)
void enc_fused(const float* __restrict__ rX, const float* __restrict__ tX,
               const __bf16* __restrict__ wb,
               const float* __restrict__ rb1, const float* __restrict__ rb2,
               const float* __restrict__ rb3,
               const float* __restrict__ tb1, const float* __restrict__ tb2,
               const float* __restrict__ tb3,
               __bf16* __restrict__ remb, __bf16* __restrict__ temb)
{
    __shared__ EncSmem sm;
    if ((int)blockIdx.x < 256)
        enc_loop<6, 64, 32>(sm, rX, wb, wb + 2048, wb + 6144,
                            rb1, rb2, rb3, remb, blockIdx.x * 32);
    else
        enc_loop<7, 128, 32>(sm, tX, wb + 8192, wb + 10240, wb + 14336,
                             tb1, tb2, tb3, temb, (blockIdx.x - 256) * 32);
}

// ---------------------------------------------------------------------------
// Head, register-chained (R7): stage c (1 barrier), then L1->L2->L3->dot in
// regs per wave (16 rows each). hw2/hw3 k-permuted; hw1/b*/w4 natural.
// ---------------------------------------------------------------------------
__global__ __launch_bounds__(256)
void head_mfma(const float* __restrict__ t0,
               const __bf16* __restrict__ remb, const __bf16* __restrict__ temb,
               const __bf16* __restrict__ hw1, const float* __restrict__ b1,
               const __bf16* __restrict__ hw2, const float* __restrict__ b2,
               const __bf16* __restrict__ hw3, const float* __restrict__ b3,
               const float* __restrict__ w4, const float* __restrict__ b4,
               float* __restrict__ out)
{
    __shared__ __align__(16) __bf16 cb[64 * 136];

    const int tid = threadIdx.x;
    const int w   = tid >> 6;
    const int l64 = tid & 63;
    const int ln  = l64 & 15;
    const int qd  = l64 >> 4;
    const int g0  = blockIdx.x * 64;

    for (int i = tid; i < 64 * 44; i += 256) {
        int r = i / 44, k = i - r * 44;
        cb[r * 136 + k] = (__bf16)t0[(size_t)(g0 + r) * 44 + k];
    }
    for (int i = tid; i < 64 * 32; i += 256) {
        int r = i >> 5, k = i & 31;
        cb[r * 136 + 44 + k] = remb[(size_t)(g0 + r) * 32 + k];
        cb[r * 136 + 76 + k] = temb[(size_t)(g0 + r) * 32 + k];
    }
    for (int i = tid; i < 64 * 20; i += 256) {
        int r = i / 20, k = i - r * 20;
        cb[r * 136 + 108 + k] = (__bf16)0.0f;
    }
    __syncthreads();

    bf16x8 cf[4];
#pragma unroll
    for (int kq = 0; kq < 4; ++kq)
        cf[kq] = ld_frag(&cb[(w * 16 + ln) * 136 + kq * 32 + qd * 8]);
    floatx4 acc1[8];
#pragma unroll
    for (int mt = 0; mt < 8; ++mt) {
        float4 bv = *(const float4*)&b1[mt * 16 + qd * 4];
        floatx4 acc = (floatx4){bv.x, bv.y, bv.z, bv.w};
#pragma unroll
        for (int kq = 0; kq < 4; ++kq) {
            bf16x8 af = ld_frag(&hw1[(mt * 16 + ln) * 128 + kq * 32 + qd * 8]);
            acc = __builtin_amdgcn_mfma_f32_16x16x32_bf16(af, cf[kq], acc, 0, 0, 0);
        }
        acc1[mt] = acc;
    }
    bf16x8 f1[4];
#pragma unroll
    for (int kq = 0; kq < 4; ++kq)
        f1[kq] = pack_relu2(acc1[2 * kq], acc1[2 * kq + 1]);

    floatx4 acc2[8];
#pragma unroll
    for (int mt = 0; mt < 8; ++mt) {
        float4 bv = *(const float4*)&b2[mt * 16 + qd * 4];
        floatx4 acc = (floatx4){bv.x, bv.y, bv.z, bv.w};
#pragma unroll
        for (int kq = 0; kq < 4; ++kq) {
            bf16x8 af = ld_frag(&hw2[(mt * 16 + ln) * 128 + kq * 32 + qd * 8]);
            acc = __builtin_amdgcn_mfma_f32_16x16x32_bf16(af, f1[kq], acc, 0, 0, 0);
        }
        acc2[mt] = acc;
    }
    bf16x8 f2[4];
#pragma unroll
    for (int kq = 0; kq < 4; ++kq)
        f2[kq] = pack_relu2(acc2[2 * kq], acc2[2 * kq + 1]);

    floatx4 acc3[4];
#pragma unroll
    for (int mt = 0; mt < 4; ++mt) {
        float4 bv = *(const float4*)&b3[mt * 16 + qd * 4];
        floatx4 acc = (floatx4){bv.x, bv.y, bv.z, bv.w};
#pragma unroll
        for (int kq = 0; kq < 4; ++kq) {
            bf16x8 af = ld_frag(&hw3[(mt * 16 + ln) * 128 + kq * 32 + qd * 8]);
            acc = __builtin_amdgcn_mfma_f32_16x16x32_bf16(af, f2[kq], acc, 0, 0, 0);
        }
        acc3[mt] = acc;
    }

    float part = 0.0f;
#pragma unroll
    for (int mt = 0; mt < 4; ++mt) {
        float4 wv = *(const float4*)&w4[mt * 16 + qd * 4];
        part = fmaf(fmaxf(acc3[mt][0], 0.0f), wv.x, part);
        part = fmaf(fmaxf(acc3[mt][1], 0.0f), wv.y, part);
        part = fmaf(fmaxf(acc3[mt][2], 0.0f), wv.z, part);
        part = fmaf(fmaxf(acc3[mt][3], 0.0f), wv.w, part);
    }
    part += __shfl_xor(part, 16);
    part += __shfl_xor(part, 32);
    if (qd == 0)
        out[g0 + w * 16 + ln] = part + b4[0];
}

extern "C" void kernel_launch(void* const* d_in, const int* in_sizes, int n_in,
                              void* d_out, int out_size, void* d_ws, size_t ws_size,
                              hipStream_t stream)
{
    const float* t0  = (const float*)d_in[0];
    const float* rX  = (const float*)d_in[1];
    const float* tX  = (const float*)d_in[2];
    const float* rw1 = (const float*)d_in[3];  const float* rb1 = (const float*)d_in[4];
    const float* rw2 = (const float*)d_in[5];  const float* rb2 = (const float*)d_in[6];
    const float* rw3 = (const float*)d_in[7];  const float* rb3 = (const float*)d_in[8];
    const float* tw1 = (const float*)d_in[9];  const float* tb1 = (const float*)d_in[10];
    const float* tw2 = (const float*)d_in[11]; const float* tb2 = (const float*)d_in[12];
    const float* tw3 = (const float*)d_in[13]; const float* tb3 = (const float*)d_in[14];
    const float* mw1 = (const float*)d_in[15]; const float* mb1 = (const float*)d_in[16];
    const float* mw2 = (const float*)d_in[17]; const float* mb2 = (const float*)d_in[18];
    const float* mw3 = (const float*)d_in[19]; const float* mb3 = (const float*)d_in[20];
    const float* mw4 = (const float*)d_in[21]; const float* mb4 = (const float*)d_in[22];
    float* out = (float*)d_out;

    const int B = 16384;
    __bf16* remb = (__bf16*)d_ws;
    __bf16* temb = (__bf16*)((char*)d_ws + ((size_t)1 << 20));
    __bf16* wb   = (__bf16*)((char*)d_ws + ((size_t)2 << 20));
    const __bf16* mw1b = wb + 16384; const __bf16* mw2b = wb + 32768;
    const __bf16* mw3b = wb + 49152;

    prep_kernel<<<64, 256, 0, stream>>>(rw1, rw2, rw3, tw1, tw2, tw3,
                                        mw1, mw2, mw3, wb);
    enc_fused<<<768, 256, 0, stream>>>(rX, tX, wb,
                                       rb1, rb2, rb3, tb1, tb2, tb3,
                                       remb, temb);
    head_mfma<<<B / 64, 256, 0, stream>>>(t0, remb, temb,
                                          mw1b, mb1, mw2b, mb2, mw3b, mb3,
                                          mw4, mb4, out);
}